// Round 3
// baseline (524.022 us; speedup 1.0000x reference)
//
#include <hip/hip_runtime.h>

#define BATCH 65536
#define HID   512
#define NCLS  1000
#define NCLSP 1024

typedef short bf16x8 __attribute__((ext_vector_type(8)));
typedef float f32x4 __attribute__((ext_vector_type(4)));
typedef unsigned short u16;
typedef unsigned int u32;

__device__ __forceinline__ u16 f2bf(float f) {
  u32 u = __float_as_uint(f);
  u += 0x7fffu + ((u >> 16) & 1u);
  return (u16)(u >> 16);
}

// ---------------- ws layout ----------------
// counts  int[1024]        @ 0
// accum   double[8]        @ 4096   (0 stab, 1 center, 2 sep, 3 brier)
// sq      float[1024]      @ 8192
// offsets int[1024]        @ 12288  (after k_scatter: segment END)
// order   int[65536]       @ 16384
// centers float[1024*512]  @ 278528
// WbFrag  u16[16*1024*32]  @ 2375680  (frag-linear bf16 W)
#define WS_END 3424256

// ---------------- label histogram ----------------
__global__ void k_hist(const int* __restrict__ labels, int* __restrict__ counts) {
  const int i = blockIdx.x * blockDim.x + threadIdx.x;
  if (i < BATCH) atomicAdd(counts + labels[i], 1);
}

// ---------------- exclusive prefix sum over 1024 bins (1 block) ----------------
__global__ void k_scan(const int* __restrict__ counts, int* __restrict__ offsets) {
  __shared__ int tmp[1024];
  const int t = threadIdx.x;
  const int v = counts[t];
  tmp[t] = v;
  __syncthreads();
  for (int d = 1; d < 1024; d <<= 1) {
    int u = (t >= d) ? tmp[t - d] : 0;
    __syncthreads();
    tmp[t] += u;
    __syncthreads();
  }
  offsets[t] = tmp[t] - v;   // exclusive
}

// ---------------- scatter row indices into class-sorted order ----------------
__global__ void k_scatter(const int* __restrict__ labels, int* __restrict__ offsets,
                          int* __restrict__ order) {
  const int i = blockIdx.x * blockDim.x + threadIdx.x;
  if (i < BATCH) {
    const int pos = atomicAdd(offsets + labels[i], 1);
    order[pos] = i;
  }
}

// ---------------- segmented mean -> centers, plus |center|^2 ----------------
__global__ void k_segsum(const float* __restrict__ cls, const int* __restrict__ order,
                         const int* __restrict__ offsets, const int* __restrict__ counts,
                         const float* __restrict__ cen_in, float* __restrict__ cen,
                         float* __restrict__ sq) {
  __shared__ float red[8];
  const int c = blockIdx.x;     // 0..1023
  const int t = threadIdx.x;    // 0..511 (one column each)
  const int cnt = counts[c];
  const int end = offsets[c];   // after scatter, offsets[c] == segment end
  const int start = end - cnt;
  float v;
  if (cnt > 0) {
    float s0 = 0.f, s1 = 0.f, s2 = 0.f, s3 = 0.f;
    int i = start;
    for (; i + 4 <= end; i += 4) {
      const int r0 = order[i], r1 = order[i + 1], r2 = order[i + 2], r3 = order[i + 3];
      s0 += cls[(size_t)r0 * HID + t];
      s1 += cls[(size_t)r1 * HID + t];
      s2 += cls[(size_t)r2 * HID + t];
      s3 += cls[(size_t)r3 * HID + t];
    }
    for (; i < end; ++i) s0 += cls[(size_t)order[i] * HID + t];
    v = ((s0 + s1) + (s2 + s3)) / (float)cnt;
  } else {
    v = (c < NCLS) ? cen_in[(size_t)c * HID + t] : 0.f;
  }
  cen[(size_t)c * HID + t] = v;
  float p = v * v;
  #pragma unroll
  for (int s = 32; s; s >>= 1) p += __shfl_xor(p, s);
  if ((t & 63) == 0) red[t >> 6] = p;
  __syncthreads();
  if (t == 0) {
    float acc = 0.f;
    #pragma unroll
    for (int i = 0; i < 8; ++i) acc += red[i];
    sq[c] = acc;
  }
}

// ---------------- W f32 -> fragment-linear bf16 ----------------
// WbFrag[((kc*1024 + col)*4 + kg)*8 + i] = W[kc*32 + kg*8 + i][col], 0 for col>=1000
__global__ void k_wconv(const float* __restrict__ W, u16* __restrict__ wb) {
  const int o = blockIdx.x * blockDim.x + threadIdx.x;   // 524288 total
  const int i = o & 7, kg = (o >> 3) & 3, col = (o >> 5) & 1023, kc = o >> 15;
  const int k = kc * 32 + kg * 8 + i;
  float v = (col < NCLS) ? W[(size_t)k * NCLS + col] : 0.f;
  wb[o] = f2bf(v);
}

// ---------------- separation: Gram + exp-sum ----------------
__global__ void k_sep(const float* __restrict__ cen, const float* __restrict__ sq,
                      double* __restrict__ accum) {
  __shared__ float As[16][64];
  __shared__ float Bs[16][64];
  __shared__ float red[4];
  const int bi = blockIdx.x >> 4, bj = blockIdx.x & 15;
  const int tx = threadIdx.x & 15, ty = threadIdx.x >> 4;
  const int lrow = threadIdx.x & 63, lkq = threadIdx.x >> 6;
  float acc[4][4] = {};
  for (int k0 = 0; k0 < HID; k0 += 16) {
    __syncthreads();
    float4 a = *(const float4*)(cen + (size_t)(bi * 64 + lrow) * HID + k0 + lkq * 4);
    float4 b = *(const float4*)(cen + (size_t)(bj * 64 + lrow) * HID + k0 + lkq * 4);
    As[lkq*4+0][lrow] = a.x; As[lkq*4+1][lrow] = a.y; As[lkq*4+2][lrow] = a.z; As[lkq*4+3][lrow] = a.w;
    Bs[lkq*4+0][lrow] = b.x; Bs[lkq*4+1][lrow] = b.y; Bs[lkq*4+2][lrow] = b.z; Bs[lkq*4+3][lrow] = b.w;
    __syncthreads();
    #pragma unroll
    for (int k = 0; k < 16; ++k) {
      float4 av = *(const float4*)&As[k][ty * 4];
      float4 bv = *(const float4*)&Bs[k][tx * 4];
      float ar[4] = {av.x, av.y, av.z, av.w};
      float br[4] = {bv.x, bv.y, bv.z, bv.w};
      #pragma unroll
      for (int r = 0; r < 4; ++r)
        #pragma unroll
        for (int s = 0; s < 4; ++s)
          acc[r][s] = fmaf(ar[r], br[s], acc[r][s]);
    }
  }
  float part = 0.f;
  #pragma unroll
  for (int r = 0; r < 4; ++r) {
    const int i = bi * 64 + ty * 4 + r;
    #pragma unroll
    for (int s = 0; s < 4; ++s) {
      const int j = bj * 64 + tx * 4 + s;
      if (i < NCLS && j < NCLS) {
        float d2 = fmaxf(sq[i] + sq[j] - 2.f * acc[r][s], 0.f);
        float dist = sqrtf(d2);
        part += __expf((i == j ? 1.f : 0.f) - dist);
      }
    }
  }
  #pragma unroll
  for (int s = 32; s; s >>= 1) part += __shfl_xor(part, s);
  if ((threadIdx.x & 63) == 0) red[threadIdx.x >> 6] = part;
  __syncthreads();
  if (threadIdx.x == 0)
    atomicAdd(accum + 2, (double)(red[0] + red[1] + red[2] + red[3]));
}

// ---------------- stab GEMM (bf16 MFMA, single-barrier) + center + brier ----------------
// BM=64 rows/block, BN=1024 (all cols), 8 waves each owning 128 cols.
// Phase 1: stage full 64x512 bf16 A-panel (cls + 0.1*noise) into XOR-swizzled LDS.
// Phase 2: one barrier; 16 barrier-free K-steps of MFMA (W frags stream from L2).
// Phase 3: stab epilogue vs logits (pulls tile into L2), then brier via L2-hot re-read.
__global__ __launch_bounds__(512, 2)
void k_stab(const float* __restrict__ cls, const float* __restrict__ noise,
            const float* __restrict__ logits, const int* __restrict__ labels,
            const float* __restrict__ bias, const float* __restrict__ cen,
            const u16* __restrict__ wb, double* __restrict__ accum) {
  __shared__ u16 As[64 * 512];   // exactly 64 KB; reused for reductions at the end
  const int lane = threadIdx.x & 63;
  const int w = threadIdx.x >> 6;
  const int row0 = blockIdx.x * 64;
  const int rl = lane >> 3;      // 0..7
  const int kb = lane & 7;       // 0..7
  const int l15 = lane & 15, lkg = lane >> 4;

  // ---- phase 1: stage A-panel + fused center loss ----
  const int row_loc = w * 8 + rl;
  const int grow = row0 + row_loc;
  const int lab = labels[grow];
  const float4* clsp = (const float4*)(cls   + (size_t)grow * HID);
  const float4* noip = (const float4*)(noise + (size_t)grow * HID);
  const float4* cenp = (const float4*)(cen   + (size_t)lab  * HID);
  float cpart = 0.f;
  #pragma unroll
  for (int i = 0; i < 8; ++i) {
    const int c = kb + 8 * i;                 // chunk 0..63 (8 floats each)
    float4 a0 = clsp[c * 2],     a1 = clsp[c * 2 + 1];
    float4 n0 = noip[c * 2],     n1 = noip[c * 2 + 1];
    float4 c0 = cenp[c * 2],     c1 = cenp[c * 2 + 1];
    float x0 = fmaf(0.1f, n0.x, a0.x), x1 = fmaf(0.1f, n0.y, a0.y);
    float x2 = fmaf(0.1f, n0.z, a0.z), x3 = fmaf(0.1f, n0.w, a0.w);
    float x4 = fmaf(0.1f, n1.x, a1.x), x5 = fmaf(0.1f, n1.y, a1.y);
    float x6 = fmaf(0.1f, n1.z, a1.z), x7 = fmaf(0.1f, n1.w, a1.w);
    float d0 = a0.x - c0.x, d1 = a0.y - c0.y, d2 = a0.z - c0.z, d3 = a0.w - c0.w;
    float d4 = a1.x - c1.x, d5 = a1.y - c1.y, d6 = a1.z - c1.z, d7 = a1.w - c1.w;
    cpart += d0*d0 + d1*d1 + d2*d2 + d3*d3 + d4*d4 + d5*d5 + d6*d6 + d7*d7;
    uint4 p;
    p.x = (u32)f2bf(x0) | ((u32)f2bf(x1) << 16);
    p.y = (u32)f2bf(x2) | ((u32)f2bf(x3) << 16);
    p.z = (u32)f2bf(x4) | ((u32)f2bf(x5) << 16);
    p.w = (u32)f2bf(x6) | ((u32)f2bf(x7) << 16);
    const int idx = row_loc * 512 + ((c * 8) ^ (rl << 3));   // T2 XOR swizzle
    *(uint4*)&As[idx] = p;
  }
  __syncthreads();

  // ---- phase 2: 16 barrier-free K-steps ----
  f32x4 acc[4][8] = {};
  const int sw = (l15 & 7) << 3;
  for (int kc = 0; kc < 16; ++kc) {
    bf16x8 af[4];
    #pragma unroll
    for (int rt = 0; rt < 4; ++rt) {
      const int row = rt * 16 + l15;
      af[rt] = *(const bf16x8*)&As[row * 512 + ((kc * 32 + lkg * 8) ^ sw)];
    }
    const u16* bbase = wb + (size_t)kc * 32768 + (w * 128 + l15) * 32 + lkg * 8;
    #pragma unroll
    for (int ct = 0; ct < 8; ++ct) {
      bf16x8 bfrag = *(const bf16x8*)(bbase + ct * 512);
      #pragma unroll
      for (int rt = 0; rt < 4; ++rt)
        acc[rt][ct] = __builtin_amdgcn_mfma_f32_16x16x32_bf16(af[rt], bfrag, acc[rt][ct], 0, 0, 0);
    }
  }

  // ---- phase 3a: stab diff^2 vs logits (C layout: col=lane&15, row=(lane>>4)*4+reg) ----
  float spart = 0.f;
  #pragma unroll
  for (int ct = 0; ct < 8; ++ct) {
    const int col = w * 128 + ct * 16 + l15;
    if (col < NCLS) {
      const float bc = bias[col];
      #pragma unroll
      for (int rt = 0; rt < 4; ++rt) {
        const int rbase = row0 + rt * 16 + lkg * 4;
        #pragma unroll
        for (int r = 0; r < 4; ++r) {
          float d = acc[rt][ct][r] + bc - logits[(size_t)(rbase + r) * NCLS + col];
          spart += d * d;
        }
      }
    }
  }
  #pragma unroll
  for (int s = 32; s; s >>= 1) { spart += __shfl_xor(spart, s); cpart += __shfl_xor(cpart, s); }

  // ---- phase 3b: brier for this block's 64 rows (logits tile is L2-hot now) ----
  float bpart = 0.f;
  for (int j = 0; j < 8; ++j) {
    const int row = row0 + w * 8 + j;
    const float4* lr = (const float4*)(logits + (size_t)row * NCLS);
    float4 v[4];
    float m = -3.4e38f;
    #pragma unroll
    for (int it = 0; it < 4; ++it) {
      const int f = it * 64 + lane;
      if (f < 250) {
        v[it] = lr[f];
        m = fmaxf(m, fmaxf(fmaxf(v[it].x, v[it].y), fmaxf(v[it].z, v[it].w)));
      }
    }
    #pragma unroll
    for (int s = 32; s; s >>= 1) m = fmaxf(m, __shfl_xor(m, s));
    const int lab2 = labels[row];
    float S = 0.f, S2 = 0.f, el = 0.f;
    #pragma unroll
    for (int it = 0; it < 4; ++it) {
      const int f = it * 64 + lane;
      if (f < 250) {
        float e0 = __expf(v[it].x - m);
        float e1 = __expf(v[it].y - m);
        float e2 = __expf(v[it].z - m);
        float e3 = __expf(v[it].w - m);
        S += e0 + e1 + e2 + e3;
        S2 += e0 * e0 + e1 * e1 + e2 * e2 + e3 * e3;
        const int c0 = f * 4;
        if (c0     == lab2) el = e0;
        if (c0 + 1 == lab2) el = e1;
        if (c0 + 2 == lab2) el = e2;
        if (c0 + 3 == lab2) el = e3;
      }
    }
    #pragma unroll
    for (int s = 32; s; s >>= 1) { S += __shfl_xor(S, s); S2 += __shfl_xor(S2, s); el += __shfl_xor(el, s); }
    bpart += S2 / (S * S) - 2.f * el / S + 1.f;
  }

  // ---- block reduce (reuse As LDS) + atomics ----
  __syncthreads();                    // all ds_reads of As done before reuse
  float* redf = (float*)As;
  if (lane == 0) { redf[w] = spart; redf[8 + w] = cpart; redf[16 + w] = bpart; }
  __syncthreads();
  if (threadIdx.x == 0) {
    float st = 0.f, ce = 0.f, br = 0.f;
    #pragma unroll
    for (int i = 0; i < 8; ++i) { st += redf[i]; ce += redf[8 + i]; br += redf[16 + i]; }
    atomicAdd(accum + 0, (double)st);
    atomicAdd(accum + 1, (double)ce);
    atomicAdd(accum + 3, (double)br);
  }
}

// ---------------- combine ----------------
__global__ void k_final(const double* __restrict__ accum, float* __restrict__ out) {
  if (threadIdx.x == 0) {
    double stab   = accum[0] / ((double)BATCH * (double)NCLS);
    double center = accum[1] / ((double)BATCH * (double)HID);
    double sep    = accum[2] - (double)NCLS;
    double brier  = accum[3] / (double)BATCH;
    double total  = 1.0 * stab + 0.1 * center + 0.01 * sep + 1.0 * brier;
    out[0] = (float)total;
    out[1] = (float)stab;
    out[2] = (float)center;
    out[3] = (float)sep;
    out[4] = (float)brier;
  }
}

extern "C" void kernel_launch(void* const* d_in, const int* in_sizes, int n_in,
                              void* d_out, int out_size, void* d_ws, size_t ws_size,
                              hipStream_t stream) {
  const float* cls    = (const float*)d_in[0];
  const float* logits = (const float*)d_in[1];
  const int*   labels = (const int*)d_in[2];
  const float* W      = (const float*)d_in[3];
  const float* bias   = (const float*)d_in[4];
  const float* noise  = (const float*)d_in[5];
  const float* cen_in = (const float*)d_in[6];
  float* out = (float*)d_out;
  char* ws = (char*)d_ws;
  if (ws_size < (size_t)WS_END) return;  // fail visibly (out stays poisoned)

  int*    counts  = (int*)(ws + 0);
  double* accum   = (double*)(ws + 4096);
  float*  sq      = (float*)(ws + 8192);
  int*    offsets = (int*)(ws + 12288);
  int*    order   = (int*)(ws + 16384);
  float*  cen     = (float*)(ws + 278528);
  u16*    wb      = (u16*)(ws + 2375680);

  hipMemsetAsync(ws, 0, 4160, stream);   // zero counts + accum
  hipLaunchKernelGGL(k_hist,    dim3(256),  dim3(256), 0, stream, labels, counts);
  hipLaunchKernelGGL(k_wconv,   dim3(2048), dim3(256), 0, stream, W, wb);
  hipLaunchKernelGGL(k_scan,    dim3(1),    dim3(1024),0, stream, counts, offsets);
  hipLaunchKernelGGL(k_scatter, dim3(256),  dim3(256), 0, stream, labels, offsets, order);
  hipLaunchKernelGGL(k_segsum,  dim3(1024), dim3(512), 0, stream, cls, order, offsets, counts, cen_in, cen, sq);
  hipLaunchKernelGGL(k_sep,     dim3(256),  dim3(256), 0, stream, cen, sq, accum);
  hipLaunchKernelGGL(k_stab,    dim3(1024), dim3(512), 0, stream, cls, noise, logits, labels, bias, cen, wb, accum);
  hipLaunchKernelGGL(k_final,   dim3(1),    dim3(64),  0, stream, accum, out);
}

// Round 4
// 418.965 us; speedup vs baseline: 1.2508x; 1.2508x over previous
//
#include <hip/hip_runtime.h>

#define BATCH 65536
#define HID   512
#define NCLS  1000
#define NCLSP 1024

typedef short bf16x8 __attribute__((ext_vector_type(8)));
typedef float f32x4 __attribute__((ext_vector_type(4)));
typedef unsigned short u16;
typedef unsigned int u32;

__device__ __forceinline__ u16 f2bf(float f) {
  u32 u = __float_as_uint(f);
  u += 0x7fffu + ((u >> 16) & 1u);
  return (u16)(u >> 16);
}

// ---------------- ws layout ----------------
// counts  int[1024]        @ 0
// accum   double[8]        @ 4096   (0 stab, 1 center, 2 sep, 3 brier)
// sq      float[1024]      @ 8192
// offsets int[1024]        @ 12288  (after k_scatter: segment END)
// order   int[65536]       @ 16384
// centers float[1024*512]  @ 278528
// WbFrag  u16[16*1024*32]  @ 2375680  (frag-linear bf16 W)
#define WS_END 3424256

// ---------------- label histogram ----------------
__global__ void k_hist(const int* __restrict__ labels, int* __restrict__ counts) {
  const int i = blockIdx.x * blockDim.x + threadIdx.x;
  if (i < BATCH) atomicAdd(counts + labels[i], 1);
}

// ---------------- exclusive prefix sum over 1024 bins (1 block) ----------------
__global__ void k_scan(const int* __restrict__ counts, int* __restrict__ offsets) {
  __shared__ int tmp[1024];
  const int t = threadIdx.x;
  const int v = counts[t];
  tmp[t] = v;
  __syncthreads();
  for (int d = 1; d < 1024; d <<= 1) {
    int u = (t >= d) ? tmp[t - d] : 0;
    __syncthreads();
    tmp[t] += u;
    __syncthreads();
  }
  offsets[t] = tmp[t] - v;   // exclusive
}

// ---------------- scatter row indices into class-sorted order ----------------
__global__ void k_scatter(const int* __restrict__ labels, int* __restrict__ offsets,
                          int* __restrict__ order) {
  const int i = blockIdx.x * blockDim.x + threadIdx.x;
  if (i < BATCH) {
    const int pos = atomicAdd(offsets + labels[i], 1);
    order[pos] = i;
  }
}

// ---------------- segmented mean -> centers, |center|^2, fused center-loss ----------------
__global__ void k_segsum(const float* __restrict__ cls, const int* __restrict__ order,
                         const int* __restrict__ offsets, const int* __restrict__ counts,
                         const float* __restrict__ cen_in, float* __restrict__ cen,
                         float* __restrict__ sq, double* __restrict__ accum) {
  __shared__ float red[8];
  __shared__ float redc[8];
  const int c = blockIdx.x;     // 0..1023
  const int t = threadIdx.x;    // 0..511 (one column each)
  const int cnt = counts[c];
  const int end = offsets[c];   // after scatter, offsets[c] == segment end
  const int start = end - cnt;
  float v;
  if (cnt > 0) {
    float s0 = 0.f, s1 = 0.f, s2 = 0.f, s3 = 0.f;
    int i = start;
    for (; i + 4 <= end; i += 4) {
      const int r0 = order[i], r1 = order[i + 1], r2 = order[i + 2], r3 = order[i + 3];
      s0 += cls[(size_t)r0 * HID + t];
      s1 += cls[(size_t)r1 * HID + t];
      s2 += cls[(size_t)r2 * HID + t];
      s3 += cls[(size_t)r3 * HID + t];
    }
    for (; i < end; ++i) s0 += cls[(size_t)order[i] * HID + t];
    v = ((s0 + s1) + (s2 + s3)) / (float)cnt;
  } else {
    v = (c < NCLS) ? cen_in[(size_t)c * HID + t] : 0.f;
  }
  cen[(size_t)c * HID + t] = v;

  // pass 2: center loss for this class's rows (L2-hot re-read)
  float cp = 0.f;
  for (int i = start; i < end; ++i) {
    float x = cls[(size_t)order[i] * HID + t] - v;
    cp += x * x;
  }

  float p = v * v;
  #pragma unroll
  for (int s = 32; s; s >>= 1) { p += __shfl_xor(p, s); cp += __shfl_xor(cp, s); }
  if ((t & 63) == 0) { red[t >> 6] = p; redc[t >> 6] = cp; }
  __syncthreads();
  if (t == 0) {
    float acc = 0.f, accc = 0.f;
    #pragma unroll
    for (int i = 0; i < 8; ++i) { acc += red[i]; accc += redc[i]; }
    sq[c] = acc;
    atomicAdd(accum + 1, (double)accc);
  }
}

// ---------------- W f32 -> fragment-linear bf16 ----------------
// WbFrag[((kc*1024 + col)*4 + kg)*8 + i] = W[kc*32 + kg*8 + i][col], 0 for col>=1000
__global__ void k_wconv(const float* __restrict__ W, u16* __restrict__ wb) {
  const int o = blockIdx.x * blockDim.x + threadIdx.x;   // 524288 total
  const int i = o & 7, kg = (o >> 3) & 3, col = (o >> 5) & 1023, kc = o >> 15;
  const int k = kc * 32 + kg * 8 + i;
  float v = (col < NCLS) ? W[(size_t)k * NCLS + col] : 0.f;
  wb[o] = f2bf(v);
}

// ---------------- separation: Gram + exp-sum ----------------
__global__ void k_sep(const float* __restrict__ cen, const float* __restrict__ sq,
                      double* __restrict__ accum) {
  __shared__ float As[16][64];
  __shared__ float Bs[16][64];
  __shared__ float red[4];
  const int bi = blockIdx.x >> 4, bj = blockIdx.x & 15;
  const int tx = threadIdx.x & 15, ty = threadIdx.x >> 4;
  const int lrow = threadIdx.x & 63, lkq = threadIdx.x >> 6;
  float acc[4][4] = {};
  for (int k0 = 0; k0 < HID; k0 += 16) {
    __syncthreads();
    float4 a = *(const float4*)(cen + (size_t)(bi * 64 + lrow) * HID + k0 + lkq * 4);
    float4 b = *(const float4*)(cen + (size_t)(bj * 64 + lrow) * HID + k0 + lkq * 4);
    As[lkq*4+0][lrow] = a.x; As[lkq*4+1][lrow] = a.y; As[lkq*4+2][lrow] = a.z; As[lkq*4+3][lrow] = a.w;
    Bs[lkq*4+0][lrow] = b.x; Bs[lkq*4+1][lrow] = b.y; Bs[lkq*4+2][lrow] = b.z; Bs[lkq*4+3][lrow] = b.w;
    __syncthreads();
    #pragma unroll
    for (int k = 0; k < 16; ++k) {
      float4 av = *(const float4*)&As[k][ty * 4];
      float4 bv = *(const float4*)&Bs[k][tx * 4];
      float ar[4] = {av.x, av.y, av.z, av.w};
      float br[4] = {bv.x, bv.y, bv.z, bv.w};
      #pragma unroll
      for (int r = 0; r < 4; ++r)
        #pragma unroll
        for (int s = 0; s < 4; ++s)
          acc[r][s] = fmaf(ar[r], br[s], acc[r][s]);
    }
  }
  float part = 0.f;
  #pragma unroll
  for (int r = 0; r < 4; ++r) {
    const int i = bi * 64 + ty * 4 + r;
    #pragma unroll
    for (int s = 0; s < 4; ++s) {
      const int j = bj * 64 + tx * 4 + s;
      if (i < NCLS && j < NCLS) {
        float d2 = fmaxf(sq[i] + sq[j] - 2.f * acc[r][s], 0.f);
        float dist = sqrtf(d2);
        part += __expf((i == j ? 1.f : 0.f) - dist);
      }
    }
  }
  #pragma unroll
  for (int s = 32; s; s >>= 1) part += __shfl_xor(part, s);
  if ((threadIdx.x & 63) == 0) red[threadIdx.x >> 6] = part;
  __syncthreads();
  if (threadIdx.x == 0)
    atomicAdd(accum + 2, (double)(red[0] + red[1] + red[2] + red[3]));
}

// ---------------- stab GEMM (bf16 MFMA) + brier ----------------
// BM=32 rows/block (2048 blocks), BN=1024, 8 waves x 128 cols, acc[2][8]=64 f32/lane.
// __launch_bounds__(512,4): cap unified regs at 128/wave -> 2 blocks (16 waves)/CU.
// Phase 1: stage 32x512 bf16 panel (cls + 0.1*noise), one barrier.
// Phase 2: 16 barrier-free K-steps (W frags from L2).
// Phase 3: brier first (coalesced logits rows -> warms L2), then strided stab-diff (L2 hits).
__global__ __launch_bounds__(512, 4)
void k_stab(const float* __restrict__ cls, const float* __restrict__ noise,
            const float* __restrict__ logits, const int* __restrict__ labels,
            const float* __restrict__ bias, const u16* __restrict__ wb,
            double* __restrict__ accum) {
  __shared__ u16 As[32 * 512];   // 32 KB; reused for reductions at the end
  const int lane = threadIdx.x & 63;
  const int w = threadIdx.x >> 6;
  const int row0 = blockIdx.x * 32;
  const int l15 = lane & 15, lkg = lane >> 4;

  // ---- phase 1: stage A-panel ----
  {
    const int row_loc = threadIdx.x >> 4;            // 0..31
    const int k0 = (threadIdx.x & 15) * 32;          // 0..480
    const float4* cp = (const float4*)(cls   + (size_t)(row0 + row_loc) * HID + k0);
    const float4* np = (const float4*)(noise + (size_t)(row0 + row_loc) * HID + k0);
    const int sw = (row_loc & 7) << 3;
    #pragma unroll
    for (int q = 0; q < 4; ++q) {
      float4 a0 = cp[q * 2], a1 = cp[q * 2 + 1];
      float4 n0 = np[q * 2], n1 = np[q * 2 + 1];
      uint4 p;
      p.x = (u32)f2bf(fmaf(0.1f, n0.x, a0.x)) | ((u32)f2bf(fmaf(0.1f, n0.y, a0.y)) << 16);
      p.y = (u32)f2bf(fmaf(0.1f, n0.z, a0.z)) | ((u32)f2bf(fmaf(0.1f, n0.w, a0.w)) << 16);
      p.z = (u32)f2bf(fmaf(0.1f, n1.x, a1.x)) | ((u32)f2bf(fmaf(0.1f, n1.y, a1.y)) << 16);
      p.w = (u32)f2bf(fmaf(0.1f, n1.z, a1.z)) | ((u32)f2bf(fmaf(0.1f, n1.w, a1.w)) << 16);
      *(uint4*)&As[row_loc * 512 + ((k0 + q * 8) ^ sw)] = p;
    }
  }
  __syncthreads();

  // ---- phase 2: 16 barrier-free K-steps ----
  f32x4 acc[2][8] = {};
  const int swr = (l15 & 7) << 3;
  for (int kc = 0; kc < 16; ++kc) {
    bf16x8 af0 = *(const bf16x8*)&As[(l15)      * 512 + ((kc * 32 + lkg * 8) ^ swr)];
    bf16x8 af1 = *(const bf16x8*)&As[(16 + l15) * 512 + ((kc * 32 + lkg * 8) ^ swr)];
    const u16* bbase = wb + (size_t)kc * 32768 + (w * 128 + l15) * 32 + lkg * 8;
    #pragma unroll
    for (int ct = 0; ct < 8; ++ct) {
      bf16x8 bfrag = *(const bf16x8*)(bbase + ct * 512);
      acc[0][ct] = __builtin_amdgcn_mfma_f32_16x16x32_bf16(af0, bfrag, acc[0][ct], 0, 0, 0);
      acc[1][ct] = __builtin_amdgcn_mfma_f32_16x16x32_bf16(af1, bfrag, acc[1][ct], 0, 0, 0);
    }
  }

  // ---- phase 3a: brier for this block's 32 rows (coalesced; warms L2) ----
  float bpart = 0.f;
  for (int j = 0; j < 4; ++j) {
    const int row = row0 + w * 4 + j;
    const float4* lr = (const float4*)(logits + (size_t)row * NCLS);
    float4 v[4];
    float m = -3.4e38f;
    #pragma unroll
    for (int it = 0; it < 4; ++it) {
      const int f = it * 64 + lane;
      if (f < 250) {
        v[it] = lr[f];
        m = fmaxf(m, fmaxf(fmaxf(v[it].x, v[it].y), fmaxf(v[it].z, v[it].w)));
      }
    }
    #pragma unroll
    for (int s = 32; s; s >>= 1) m = fmaxf(m, __shfl_xor(m, s));
    const int lab2 = labels[row];
    float S = 0.f, S2 = 0.f, el = 0.f;
    #pragma unroll
    for (int it = 0; it < 4; ++it) {
      const int f = it * 64 + lane;
      if (f < 250) {
        float e0 = __expf(v[it].x - m);
        float e1 = __expf(v[it].y - m);
        float e2 = __expf(v[it].z - m);
        float e3 = __expf(v[it].w - m);
        S += e0 + e1 + e2 + e3;
        S2 += e0 * e0 + e1 * e1 + e2 * e2 + e3 * e3;
        const int c0 = f * 4;
        if (c0     == lab2) el = e0;
        if (c0 + 1 == lab2) el = e1;
        if (c0 + 2 == lab2) el = e2;
        if (c0 + 3 == lab2) el = e3;
      }
    }
    #pragma unroll
    for (int s = 32; s; s >>= 1) { S += __shfl_xor(S, s); S2 += __shfl_xor(S2, s); el += __shfl_xor(el, s); }
    bpart += S2 / (S * S) - 2.f * el / S + 1.f;
  }

  // ---- phase 3b: stab diff^2 vs logits (L2-hot strided reads) ----
  float spart = 0.f;
  #pragma unroll
  for (int ct = 0; ct < 8; ++ct) {
    const int col = w * 128 + ct * 16 + l15;
    if (col < NCLS) {
      const float bc = bias[col];
      #pragma unroll
      for (int rt = 0; rt < 2; ++rt) {
        const int rbase = row0 + rt * 16 + lkg * 4;
        #pragma unroll
        for (int r = 0; r < 4; ++r) {
          float d = acc[rt][ct][r] + bc - logits[(size_t)(rbase + r) * NCLS + col];
          spart += d * d;
        }
      }
    }
  }
  #pragma unroll
  for (int s = 32; s; s >>= 1) { spart += __shfl_xor(spart, s); bpart += __shfl_xor(bpart, s); }

  // ---- block reduce (reuse As LDS) + atomics ----
  __syncthreads();                    // all ds_reads of As done before reuse
  float* redf = (float*)As;
  if (lane == 0) { redf[w] = spart; redf[8 + w] = bpart; }
  __syncthreads();
  if (threadIdx.x == 0) {
    float st = 0.f, br = 0.f;
    #pragma unroll
    for (int i = 0; i < 8; ++i) { st += redf[i]; br += redf[8 + i]; }
    atomicAdd(accum + 0, (double)st);
    atomicAdd(accum + 3, (double)br);
  }
}

// ---------------- combine ----------------
__global__ void k_final(const double* __restrict__ accum, float* __restrict__ out) {
  if (threadIdx.x == 0) {
    double stab   = accum[0] / ((double)BATCH * (double)NCLS);
    double center = accum[1] / ((double)BATCH * (double)HID);
    double sep    = accum[2] - (double)NCLS;
    double brier  = accum[3] / (double)BATCH;
    double total  = 1.0 * stab + 0.1 * center + 0.01 * sep + 1.0 * brier;
    out[0] = (float)total;
    out[1] = (float)stab;
    out[2] = (float)center;
    out[3] = (float)sep;
    out[4] = (float)brier;
  }
}

extern "C" void kernel_launch(void* const* d_in, const int* in_sizes, int n_in,
                              void* d_out, int out_size, void* d_ws, size_t ws_size,
                              hipStream_t stream) {
  const float* cls    = (const float*)d_in[0];
  const float* logits = (const float*)d_in[1];
  const int*   labels = (const int*)d_in[2];
  const float* W      = (const float*)d_in[3];
  const float* bias   = (const float*)d_in[4];
  const float* noise  = (const float*)d_in[5];
  const float* cen_in = (const float*)d_in[6];
  float* out = (float*)d_out;
  char* ws = (char*)d_ws;
  if (ws_size < (size_t)WS_END) return;  // fail visibly (out stays poisoned)

  int*    counts  = (int*)(ws + 0);
  double* accum   = (double*)(ws + 4096);
  float*  sq      = (float*)(ws + 8192);
  int*    offsets = (int*)(ws + 12288);
  int*    order   = (int*)(ws + 16384);
  float*  cen     = (float*)(ws + 278528);
  u16*    wb      = (u16*)(ws + 2375680);

  hipMemsetAsync(ws, 0, 4160, stream);   // zero counts + accum
  hipLaunchKernelGGL(k_hist,    dim3(256),  dim3(256), 0, stream, labels, counts);
  hipLaunchKernelGGL(k_wconv,   dim3(2048), dim3(256), 0, stream, W, wb);
  hipLaunchKernelGGL(k_scan,    dim3(1),    dim3(1024),0, stream, counts, offsets);
  hipLaunchKernelGGL(k_scatter, dim3(256),  dim3(256), 0, stream, labels, offsets, order);
  hipLaunchKernelGGL(k_segsum,  dim3(1024), dim3(512), 0, stream, cls, order, offsets, counts, cen_in, cen, sq, accum);
  hipLaunchKernelGGL(k_sep,     dim3(256),  dim3(256), 0, stream, cen, sq, accum);
  hipLaunchKernelGGL(k_stab,    dim3(2048), dim3(512), 0, stream, cls, noise, logits, labels, bias, wb, accum);
  hipLaunchKernelGGL(k_final,   dim3(1),    dim3(64),  0, stream, accum, out);
}

// Round 5
// 416.183 us; speedup vs baseline: 1.2591x; 1.0067x over previous
//
#include <hip/hip_runtime.h>

#define BATCH 65536
#define HID   512
#define NCLS  1000
#define NCLSP 1024

typedef short bf16x8 __attribute__((ext_vector_type(8)));
typedef float f32x4 __attribute__((ext_vector_type(4)));
typedef unsigned short u16;
typedef unsigned int u32;

__device__ __forceinline__ u16 f2bf(float f) {
  u32 u = __float_as_uint(f);
  u += 0x7fffu + ((u >> 16) & 1u);
  return (u16)(u >> 16);
}

// ---------------- ws layout ----------------
// counts  int[1024]        @ 0
// accum   double[8]        @ 4096   (0 stab, 1 center, 2 sep, 3 brier)
// sq      float[1024]      @ 8192
// offsets int[1024]        @ 12288  (after k_scatter: segment END)
// order   int[65536]       @ 16384
// centers float[1024*512]  @ 278528
// WbFrag  u16[16*1024*32]  @ 2375680  (frag-linear bf16 W)
// panel   u16[65536*512]   @ 3424256  (pre-swizzled bf16 cls+0.1*noise; 64 MB)
#define WS_END 3424256
#define WS_BIG 70533120

// ---------------- label histogram ----------------
__global__ void k_hist(const int* __restrict__ labels, int* __restrict__ counts) {
  const int i = blockIdx.x * blockDim.x + threadIdx.x;
  if (i < BATCH) atomicAdd(counts + labels[i], 1);
}

// ---------------- exclusive prefix sum over 1024 bins (1 block) ----------------
__global__ void k_scan(const int* __restrict__ counts, int* __restrict__ offsets) {
  __shared__ int tmp[1024];
  const int t = threadIdx.x;
  const int v = counts[t];
  tmp[t] = v;
  __syncthreads();
  for (int d = 1; d < 1024; d <<= 1) {
    int u = (t >= d) ? tmp[t - d] : 0;
    __syncthreads();
    tmp[t] += u;
    __syncthreads();
  }
  offsets[t] = tmp[t] - v;   // exclusive
}

// ---------------- scatter row indices into class-sorted order ----------------
__global__ void k_scatter(const int* __restrict__ labels, int* __restrict__ offsets,
                          int* __restrict__ order) {
  const int i = blockIdx.x * blockDim.x + threadIdx.x;
  if (i < BATCH) {
    const int pos = atomicAdd(offsets + labels[i], 1);
    order[pos] = i;
  }
}

// ---------------- segmented mean -> centers, |center|^2, fused center-loss ----------------
__global__ void k_segsum(const float* __restrict__ cls, const int* __restrict__ order,
                         const int* __restrict__ offsets, const int* __restrict__ counts,
                         const float* __restrict__ cen_in, float* __restrict__ cen,
                         float* __restrict__ sq, double* __restrict__ accum) {
  __shared__ float red[8];
  __shared__ float redc[8];
  const int c = blockIdx.x;     // 0..1023
  const int t = threadIdx.x;    // 0..511 (one column each)
  const int cnt = counts[c];
  const int end = offsets[c];   // after scatter, offsets[c] == segment end
  const int start = end - cnt;
  float v;
  if (cnt > 0) {
    float s0 = 0.f, s1 = 0.f, s2 = 0.f, s3 = 0.f;
    int i = start;
    for (; i + 4 <= end; i += 4) {
      const int r0 = order[i], r1 = order[i + 1], r2 = order[i + 2], r3 = order[i + 3];
      s0 += cls[(size_t)r0 * HID + t];
      s1 += cls[(size_t)r1 * HID + t];
      s2 += cls[(size_t)r2 * HID + t];
      s3 += cls[(size_t)r3 * HID + t];
    }
    for (; i < end; ++i) s0 += cls[(size_t)order[i] * HID + t];
    v = ((s0 + s1) + (s2 + s3)) / (float)cnt;
  } else {
    v = (c < NCLS) ? cen_in[(size_t)c * HID + t] : 0.f;
  }
  cen[(size_t)c * HID + t] = v;

  // pass 2: center loss for this class's rows (L2/L3-hot re-read)
  float cp = 0.f;
  for (int i = start; i < end; ++i) {
    float x = cls[(size_t)order[i] * HID + t] - v;
    cp += x * x;
  }

  float p = v * v;
  #pragma unroll
  for (int s = 32; s; s >>= 1) { p += __shfl_xor(p, s); cp += __shfl_xor(cp, s); }
  if ((t & 63) == 0) { red[t >> 6] = p; redc[t >> 6] = cp; }
  __syncthreads();
  if (t == 0) {
    float acc = 0.f, accc = 0.f;
    #pragma unroll
    for (int i = 0; i < 8; ++i) { acc += red[i]; accc += redc[i]; }
    sq[c] = acc;
    atomicAdd(accum + 1, (double)accc);
  }
}

// ---------------- W f32 -> fragment-linear bf16 ----------------
// WbFrag[((kc*1024 + col)*4 + kg)*8 + i] = W[kc*32 + kg*8 + i][col], 0 for col>=1000
__global__ void k_wconv(const float* __restrict__ W, u16* __restrict__ wb) {
  const int o = blockIdx.x * blockDim.x + threadIdx.x;   // 524288 total
  const int i = o & 7, kg = (o >> 3) & 3, col = (o >> 5) & 1023, kc = o >> 15;
  const int k = kc * 32 + kg * 8 + i;
  float v = (col < NCLS) ? W[(size_t)k * NCLS + col] : 0.f;
  wb[o] = f2bf(v);
}

// ---------------- separation: Gram + exp-sum ----------------
__global__ void k_sep(const float* __restrict__ cen, const float* __restrict__ sq,
                      double* __restrict__ accum) {
  __shared__ float As[16][64];
  __shared__ float Bs[16][64];
  __shared__ float red[4];
  const int bi = blockIdx.x >> 4, bj = blockIdx.x & 15;
  const int tx = threadIdx.x & 15, ty = threadIdx.x >> 4;
  const int lrow = threadIdx.x & 63, lkq = threadIdx.x >> 6;
  float acc[4][4] = {};
  for (int k0 = 0; k0 < HID; k0 += 16) {
    __syncthreads();
    float4 a = *(const float4*)(cen + (size_t)(bi * 64 + lrow) * HID + k0 + lkq * 4);
    float4 b = *(const float4*)(cen + (size_t)(bj * 64 + lrow) * HID + k0 + lkq * 4);
    As[lkq*4+0][lrow] = a.x; As[lkq*4+1][lrow] = a.y; As[lkq*4+2][lrow] = a.z; As[lkq*4+3][lrow] = a.w;
    Bs[lkq*4+0][lrow] = b.x; Bs[lkq*4+1][lrow] = b.y; Bs[lkq*4+2][lrow] = b.z; Bs[lkq*4+3][lrow] = b.w;
    __syncthreads();
    #pragma unroll
    for (int k = 0; k < 16; ++k) {
      float4 av = *(const float4*)&As[k][ty * 4];
      float4 bv = *(const float4*)&Bs[k][tx * 4];
      float ar[4] = {av.x, av.y, av.z, av.w};
      float br[4] = {bv.x, bv.y, bv.z, bv.w};
      #pragma unroll
      for (int r = 0; r < 4; ++r)
        #pragma unroll
        for (int s = 0; s < 4; ++s)
          acc[r][s] = fmaf(ar[r], br[s], acc[r][s]);
    }
  }
  float part = 0.f;
  #pragma unroll
  for (int r = 0; r < 4; ++r) {
    const int i = bi * 64 + ty * 4 + r;
    #pragma unroll
    for (int s = 0; s < 4; ++s) {
      const int j = bj * 64 + tx * 4 + s;
      if (i < NCLS && j < NCLS) {
        float d2 = fmaxf(sq[i] + sq[j] - 2.f * acc[r][s], 0.f);
        float dist = sqrtf(d2);
        part += __expf((i == j ? 1.f : 0.f) - dist);
      }
    }
  }
  #pragma unroll
  for (int s = 32; s; s >>= 1) part += __shfl_xor(part, s);
  if ((threadIdx.x & 63) == 0) red[threadIdx.x >> 6] = part;
  __syncthreads();
  if (threadIdx.x == 0)
    atomicAdd(accum + 2, (double)(red[0] + red[1] + red[2] + red[3]));
}

// ---------------- prep: bf16 panel x = cls + 0.1*noise, pre-swizzled ----------------
// panel[row*512 + koff] holds x[row][koff ^ ((row&7)<<3)] (XOR is an involution on bits 3-5)
__global__ void k_prep(const float* __restrict__ cls, const float* __restrict__ noise,
                       u16* __restrict__ panel) {
  const int nth = gridDim.x * blockDim.x;
  for (int c = blockIdx.x * blockDim.x + threadIdx.x; c < BATCH * 64; c += nth) {
    const int row = c >> 6;
    const int koff = (c & 63) * 8;
    const int k = koff ^ ((row & 7) << 3);
    const float4* cp = (const float4*)(cls   + (size_t)row * HID + k);
    const float4* np = (const float4*)(noise + (size_t)row * HID + k);
    float4 a0 = cp[0], a1 = cp[1];
    float4 n0 = np[0], n1 = np[1];
    uint4 p;
    p.x = (u32)f2bf(fmaf(0.1f, n0.x, a0.x)) | ((u32)f2bf(fmaf(0.1f, n0.y, a0.y)) << 16);
    p.y = (u32)f2bf(fmaf(0.1f, n0.z, a0.z)) | ((u32)f2bf(fmaf(0.1f, n0.w, a0.w)) << 16);
    p.z = (u32)f2bf(fmaf(0.1f, n1.x, a1.x)) | ((u32)f2bf(fmaf(0.1f, n1.y, a1.y)) << 16);
    p.w = (u32)f2bf(fmaf(0.1f, n1.z, a1.z)) | ((u32)f2bf(fmaf(0.1f, n1.w, a1.w)) << 16);
    *(uint4*)&panel[(size_t)row * 512 + koff] = p;
  }
}

// ---------------- GEMM (bf16 MFMA, global_load_lds staging) + brier + stab ----------------
// BM=32 rows/block (2048 blocks), BN=1024, 8 waves x 128 cols, acc[2][8]=64 f32/lane.
__global__ __launch_bounds__(512, 4)
void k_gemm(const u16* __restrict__ panel, const float* __restrict__ logits,
            const int* __restrict__ labels, const float* __restrict__ bias,
            const u16* __restrict__ wb, double* __restrict__ accum) {
  __shared__ u16 As[32 * 512];   // 32 KB; reused for reductions at the end
  const int lane = threadIdx.x & 63;
  const int w = threadIdx.x >> 6;
  const int row0 = blockIdx.x * 32;
  const int l15 = lane & 15, lkg = lane >> 4;

  // ---- phase 1: DMA the pre-swizzled 32x512 bf16 tile into LDS (width-16) ----
  {
    const u16* src = panel + (size_t)blockIdx.x * 16384;
    #pragma unroll
    for (int r = 0; r < 4; ++r) {
      const int seg = r * 8 + w;                    // 1 KB segment per wave-issue
      const u16* g = src + seg * 512 + lane * 8;    // per-lane global source
      u16* l = As + seg * 512;                      // wave-uniform LDS dest
      __builtin_amdgcn_global_load_lds((const __attribute__((address_space(1))) void*)g,
                                       (__attribute__((address_space(3))) void*)l,
                                       16, 0, 0);
    }
  }
  __syncthreads();

  // ---- phase 2: 16 barrier-free K-steps ----
  f32x4 acc[2][8] = {};
  const int swr = (l15 & 7) << 3;
  for (int kc = 0; kc < 16; ++kc) {
    bf16x8 af0 = *(const bf16x8*)&As[(l15)      * 512 + ((kc * 32 + lkg * 8) ^ swr)];
    bf16x8 af1 = *(const bf16x8*)&As[(16 + l15) * 512 + ((kc * 32 + lkg * 8) ^ swr)];
    const u16* bbase = wb + (size_t)kc * 32768 + (w * 128 + l15) * 32 + lkg * 8;
    #pragma unroll
    for (int ct = 0; ct < 8; ++ct) {
      bf16x8 bfrag = *(const bf16x8*)(bbase + ct * 512);
      acc[0][ct] = __builtin_amdgcn_mfma_f32_16x16x32_bf16(af0, bfrag, acc[0][ct], 0, 0, 0);
      acc[1][ct] = __builtin_amdgcn_mfma_f32_16x16x32_bf16(af1, bfrag, acc[1][ct], 0, 0, 0);
    }
  }

  // ---- phase 3a: brier for this block's 32 rows (coalesced; warms L2) ----
  float bpart = 0.f;
  for (int j = 0; j < 4; ++j) {
    const int row = row0 + w * 4 + j;
    const float4* lr = (const float4*)(logits + (size_t)row * NCLS);
    float4 v[4];
    float m = -3.4e38f;
    #pragma unroll
    for (int it = 0; it < 4; ++it) {
      const int f = it * 64 + lane;
      if (f < 250) {
        v[it] = lr[f];
        m = fmaxf(m, fmaxf(fmaxf(v[it].x, v[it].y), fmaxf(v[it].z, v[it].w)));
      }
    }
    #pragma unroll
    for (int s = 32; s; s >>= 1) m = fmaxf(m, __shfl_xor(m, s));
    const int lab2 = labels[row];
    float S = 0.f, S2 = 0.f, el = 0.f;
    #pragma unroll
    for (int it = 0; it < 4; ++it) {
      const int f = it * 64 + lane;
      if (f < 250) {
        float e0 = __expf(v[it].x - m);
        float e1 = __expf(v[it].y - m);
        float e2 = __expf(v[it].z - m);
        float e3 = __expf(v[it].w - m);
        S += e0 + e1 + e2 + e3;
        S2 += e0 * e0 + e1 * e1 + e2 * e2 + e3 * e3;
        const int c0 = f * 4;
        if (c0     == lab2) el = e0;
        if (c0 + 1 == lab2) el = e1;
        if (c0 + 2 == lab2) el = e2;
        if (c0 + 3 == lab2) el = e3;
      }
    }
    #pragma unroll
    for (int s = 32; s; s >>= 1) { S += __shfl_xor(S, s); S2 += __shfl_xor(S2, s); el += __shfl_xor(el, s); }
    bpart += S2 / (S * S) - 2.f * el / S + 1.f;
  }

  // ---- phase 3b: stab diff^2 vs logits (L2-hot strided reads) ----
  float spart = 0.f;
  #pragma unroll
  for (int ct = 0; ct < 8; ++ct) {
    const int col = w * 128 + ct * 16 + l15;
    if (col < NCLS) {
      const float bc = bias[col];
      #pragma unroll
      for (int rt = 0; rt < 2; ++rt) {
        const int rbase = row0 + rt * 16 + lkg * 4;
        #pragma unroll
        for (int r = 0; r < 4; ++r) {
          float d = acc[rt][ct][r] + bc - logits[(size_t)(rbase + r) * NCLS + col];
          spart += d * d;
        }
      }
    }
  }
  #pragma unroll
  for (int s = 32; s; s >>= 1) { spart += __shfl_xor(spart, s); bpart += __shfl_xor(bpart, s); }

  // ---- block reduce (reuse As LDS) + atomics ----
  __syncthreads();                    // all ds_reads of As done before reuse
  float* redf = (float*)As;
  if (lane == 0) { redf[w] = spart; redf[8 + w] = bpart; }
  __syncthreads();
  if (threadIdx.x == 0) {
    float st = 0.f, br = 0.f;
    #pragma unroll
    for (int i = 0; i < 8; ++i) { st += redf[i]; br += redf[8 + i]; }
    atomicAdd(accum + 0, (double)st);
    atomicAdd(accum + 3, (double)br);
  }
}

// ---------------- fallback fused stab (round-4 path, used if ws too small) ----------------
__global__ __launch_bounds__(512, 4)
void k_stab_fb(const float* __restrict__ cls, const float* __restrict__ noise,
               const float* __restrict__ logits, const int* __restrict__ labels,
               const float* __restrict__ bias, const u16* __restrict__ wb,
               double* __restrict__ accum) {
  __shared__ u16 As[32 * 512];
  const int lane = threadIdx.x & 63;
  const int w = threadIdx.x >> 6;
  const int row0 = blockIdx.x * 32;
  const int l15 = lane & 15, lkg = lane >> 4;
  {
    const int row_loc = threadIdx.x >> 4;
    const int k0 = (threadIdx.x & 15) * 32;
    const float4* cp = (const float4*)(cls   + (size_t)(row0 + row_loc) * HID + k0);
    const float4* np = (const float4*)(noise + (size_t)(row0 + row_loc) * HID + k0);
    const int sw = (row_loc & 7) << 3;
    #pragma unroll
    for (int q = 0; q < 4; ++q) {
      float4 a0 = cp[q * 2], a1 = cp[q * 2 + 1];
      float4 n0 = np[q * 2], n1 = np[q * 2 + 1];
      uint4 p;
      p.x = (u32)f2bf(fmaf(0.1f, n0.x, a0.x)) | ((u32)f2bf(fmaf(0.1f, n0.y, a0.y)) << 16);
      p.y = (u32)f2bf(fmaf(0.1f, n0.z, a0.z)) | ((u32)f2bf(fmaf(0.1f, n0.w, a0.w)) << 16);
      p.z = (u32)f2bf(fmaf(0.1f, n1.x, a1.x)) | ((u32)f2bf(fmaf(0.1f, n1.y, a1.y)) << 16);
      p.w = (u32)f2bf(fmaf(0.1f, n1.z, a1.z)) | ((u32)f2bf(fmaf(0.1f, n1.w, a1.w)) << 16);
      *(uint4*)&As[row_loc * 512 + ((k0 + q * 8) ^ sw)] = p;
    }
  }
  __syncthreads();
  f32x4 acc[2][8] = {};
  const int swr = (l15 & 7) << 3;
  for (int kc = 0; kc < 16; ++kc) {
    bf16x8 af0 = *(const bf16x8*)&As[(l15)      * 512 + ((kc * 32 + lkg * 8) ^ swr)];
    bf16x8 af1 = *(const bf16x8*)&As[(16 + l15) * 512 + ((kc * 32 + lkg * 8) ^ swr)];
    const u16* bbase = wb + (size_t)kc * 32768 + (w * 128 + l15) * 32 + lkg * 8;
    #pragma unroll
    for (int ct = 0; ct < 8; ++ct) {
      bf16x8 bfrag = *(const bf16x8*)(bbase + ct * 512);
      acc[0][ct] = __builtin_amdgcn_mfma_f32_16x16x32_bf16(af0, bfrag, acc[0][ct], 0, 0, 0);
      acc[1][ct] = __builtin_amdgcn_mfma_f32_16x16x32_bf16(af1, bfrag, acc[1][ct], 0, 0, 0);
    }
  }
  float bpart = 0.f;
  for (int j = 0; j < 4; ++j) {
    const int row = row0 + w * 4 + j;
    const float4* lr = (const float4*)(logits + (size_t)row * NCLS);
    float4 v[4];
    float m = -3.4e38f;
    #pragma unroll
    for (int it = 0; it < 4; ++it) {
      const int f = it * 64 + lane;
      if (f < 250) {
        v[it] = lr[f];
        m = fmaxf(m, fmaxf(fmaxf(v[it].x, v[it].y), fmaxf(v[it].z, v[it].w)));
      }
    }
    #pragma unroll
    for (int s = 32; s; s >>= 1) m = fmaxf(m, __shfl_xor(m, s));
    const int lab2 = labels[row];
    float S = 0.f, S2 = 0.f, el = 0.f;
    #pragma unroll
    for (int it = 0; it < 4; ++it) {
      const int f = it * 64 + lane;
      if (f < 250) {
        float e0 = __expf(v[it].x - m);
        float e1 = __expf(v[it].y - m);
        float e2 = __expf(v[it].z - m);
        float e3 = __expf(v[it].w - m);
        S += e0 + e1 + e2 + e3;
        S2 += e0 * e0 + e1 * e1 + e2 * e2 + e3 * e3;
        const int c0 = f * 4;
        if (c0     == lab2) el = e0;
        if (c0 + 1 == lab2) el = e1;
        if (c0 + 2 == lab2) el = e2;
        if (c0 + 3 == lab2) el = e3;
      }
    }
    #pragma unroll
    for (int s = 32; s; s >>= 1) { S += __shfl_xor(S, s); S2 += __shfl_xor(S2, s); el += __shfl_xor(el, s); }
    bpart += S2 / (S * S) - 2.f * el / S + 1.f;
  }
  float spart = 0.f;
  #pragma unroll
  for (int ct = 0; ct < 8; ++ct) {
    const int col = w * 128 + ct * 16 + l15;
    if (col < NCLS) {
      const float bc = bias[col];
      #pragma unroll
      for (int rt = 0; rt < 2; ++rt) {
        const int rbase = row0 + rt * 16 + lkg * 4;
        #pragma unroll
        for (int r = 0; r < 4; ++r) {
          float d = acc[rt][ct][r] + bc - logits[(size_t)(rbase + r) * NCLS + col];
          spart += d * d;
        }
      }
    }
  }
  #pragma unroll
  for (int s = 32; s; s >>= 1) { spart += __shfl_xor(spart, s); bpart += __shfl_xor(bpart, s); }
  __syncthreads();
  float* redf = (float*)As;
  if (lane == 0) { redf[w] = spart; redf[8 + w] = bpart; }
  __syncthreads();
  if (threadIdx.x == 0) {
    float st = 0.f, br = 0.f;
    #pragma unroll
    for (int i = 0; i < 8; ++i) { st += redf[i]; br += redf[8 + i]; }
    atomicAdd(accum + 0, (double)st);
    atomicAdd(accum + 3, (double)br);
  }
}

// ---------------- combine ----------------
__global__ void k_final(const double* __restrict__ accum, float* __restrict__ out) {
  if (threadIdx.x == 0) {
    double stab   = accum[0] / ((double)BATCH * (double)NCLS);
    double center = accum[1] / ((double)BATCH * (double)HID);
    double sep    = accum[2] - (double)NCLS;
    double brier  = accum[3] / (double)BATCH;
    double total  = 1.0 * stab + 0.1 * center + 0.01 * sep + 1.0 * brier;
    out[0] = (float)total;
    out[1] = (float)stab;
    out[2] = (float)center;
    out[3] = (float)sep;
    out[4] = (float)brier;
  }
}

extern "C" void kernel_launch(void* const* d_in, const int* in_sizes, int n_in,
                              void* d_out, int out_size, void* d_ws, size_t ws_size,
                              hipStream_t stream) {
  const float* cls    = (const float*)d_in[0];
  const float* logits = (const float*)d_in[1];
  const int*   labels = (const int*)d_in[2];
  const float* W      = (const float*)d_in[3];
  const float* bias   = (const float*)d_in[4];
  const float* noise  = (const float*)d_in[5];
  const float* cen_in = (const float*)d_in[6];
  float* out = (float*)d_out;
  char* ws = (char*)d_ws;
  if (ws_size < (size_t)WS_END) return;  // fail visibly (out stays poisoned)

  int*    counts  = (int*)(ws + 0);
  double* accum   = (double*)(ws + 4096);
  float*  sq      = (float*)(ws + 8192);
  int*    offsets = (int*)(ws + 12288);
  int*    order   = (int*)(ws + 16384);
  float*  cen     = (float*)(ws + 278528);
  u16*    wb      = (u16*)(ws + 2375680);
  u16*    panel   = (u16*)(ws + 3424256);

  hipMemsetAsync(ws, 0, 4160, stream);   // zero counts + accum
  hipLaunchKernelGGL(k_hist,    dim3(256),  dim3(256), 0, stream, labels, counts);
  hipLaunchKernelGGL(k_wconv,   dim3(2048), dim3(256), 0, stream, W, wb);
  hipLaunchKernelGGL(k_scan,    dim3(1),    dim3(1024),0, stream, counts, offsets);
  hipLaunchKernelGGL(k_scatter, dim3(256),  dim3(256), 0, stream, labels, offsets, order);
  hipLaunchKernelGGL(k_segsum,  dim3(1024), dim3(512), 0, stream, cls, order, offsets, counts, cen_in, cen, sq, accum);
  hipLaunchKernelGGL(k_sep,     dim3(256),  dim3(256), 0, stream, cen, sq, accum);
  if (ws_size >= (size_t)WS_BIG) {
    hipLaunchKernelGGL(k_prep,  dim3(2048), dim3(256), 0, stream, cls, noise, panel);
    hipLaunchKernelGGL(k_gemm,  dim3(2048), dim3(512), 0, stream, panel, logits, labels, bias, wb, accum);
  } else {
    hipLaunchKernelGGL(k_stab_fb, dim3(2048), dim3(512), 0, stream, cls, noise, logits, labels, bias, wb, accum);
  }
  hipLaunchKernelGGL(k_final,   dim3(1),    dim3(64),  0, stream, accum, out);
}

// Round 6
// 383.328 us; speedup vs baseline: 1.3670x; 1.0857x over previous
//
#include <hip/hip_runtime.h>

#define BATCH 65536
#define HID   512
#define NCLS  1000
#define NCLSP 1024

typedef short bf16x8 __attribute__((ext_vector_type(8)));
typedef float f32x4 __attribute__((ext_vector_type(4)));
typedef unsigned short u16;
typedef unsigned int u32;

__device__ __forceinline__ u16 f2bf(float f) {
  u32 u = __float_as_uint(f);
  u += 0x7fffu + ((u >> 16) & 1u);
  return (u16)(u >> 16);
}

// ---------------- ws layout ----------------
// counts  int[1024]        @ 0
// accum   double[8]        @ 4096   (0 stab, 1 center, 2 sep, 3 brier)
// sq      float[1024]      @ 8192
// offsets int[1024]        @ 12288  (after k_scatter: segment END)
// order   int[65536]       @ 16384
// centers float[1024*512]  @ 278528
// WbFrag  u16[16*1024*32]  @ 2375680  (frag-linear bf16 W)
// panel   u16[65536*512]   @ 3424256  (pre-swizzled bf16 cls+0.1*noise; 64 MB)
#define WS_END 3424256
#define WS_BIG 70533120

// ---------------- label histogram ----------------
__global__ void k_hist(const int* __restrict__ labels, int* __restrict__ counts) {
  const int i = blockIdx.x * blockDim.x + threadIdx.x;
  if (i < BATCH) atomicAdd(counts + labels[i], 1);
}

// ---------------- exclusive prefix sum over 1024 bins (1 block) ----------------
__global__ void k_scan(const int* __restrict__ counts, int* __restrict__ offsets) {
  __shared__ int tmp[1024];
  const int t = threadIdx.x;
  const int v = counts[t];
  tmp[t] = v;
  __syncthreads();
  for (int d = 1; d < 1024; d <<= 1) {
    int u = (t >= d) ? tmp[t - d] : 0;
    __syncthreads();
    tmp[t] += u;
    __syncthreads();
  }
  offsets[t] = tmp[t] - v;   // exclusive
}

// ---------------- scatter row indices into class-sorted order ----------------
__global__ void k_scatter(const int* __restrict__ labels, int* __restrict__ offsets,
                          int* __restrict__ order) {
  const int i = blockIdx.x * blockDim.x + threadIdx.x;
  if (i < BATCH) {
    const int pos = atomicAdd(offsets + labels[i], 1);
    order[pos] = i;
  }
}

// ---------------- segmented mean -> centers, |center|^2, fused center-loss ----------------
__global__ void k_segsum(const float* __restrict__ cls, const int* __restrict__ order,
                         const int* __restrict__ offsets, const int* __restrict__ counts,
                         const float* __restrict__ cen_in, float* __restrict__ cen,
                         float* __restrict__ sq, double* __restrict__ accum) {
  __shared__ float red[8];
  __shared__ float redc[8];
  const int c = blockIdx.x;     // 0..1023
  const int t = threadIdx.x;    // 0..511 (one column each)
  const int cnt = counts[c];
  const int end = offsets[c];   // after scatter, offsets[c] == segment end
  const int start = end - cnt;
  float v;
  if (cnt > 0) {
    float s0 = 0.f, s1 = 0.f, s2 = 0.f, s3 = 0.f;
    int i = start;
    for (; i + 4 <= end; i += 4) {
      const int r0 = order[i], r1 = order[i + 1], r2 = order[i + 2], r3 = order[i + 3];
      s0 += cls[(size_t)r0 * HID + t];
      s1 += cls[(size_t)r1 * HID + t];
      s2 += cls[(size_t)r2 * HID + t];
      s3 += cls[(size_t)r3 * HID + t];
    }
    for (; i < end; ++i) s0 += cls[(size_t)order[i] * HID + t];
    v = ((s0 + s1) + (s2 + s3)) / (float)cnt;
  } else {
    v = (c < NCLS) ? cen_in[(size_t)c * HID + t] : 0.f;
  }
  cen[(size_t)c * HID + t] = v;

  // pass 2: center loss for this class's rows (L2/L3-hot re-read)
  float cp = 0.f;
  for (int i = start; i < end; ++i) {
    float x = cls[(size_t)order[i] * HID + t] - v;
    cp += x * x;
  }

  float p = v * v;
  #pragma unroll
  for (int s = 32; s; s >>= 1) { p += __shfl_xor(p, s); cp += __shfl_xor(cp, s); }
  if ((t & 63) == 0) { red[t >> 6] = p; redc[t >> 6] = cp; }
  __syncthreads();
  if (t == 0) {
    float acc = 0.f, accc = 0.f;
    #pragma unroll
    for (int i = 0; i < 8; ++i) { acc += red[i]; accc += redc[i]; }
    sq[c] = acc;
    atomicAdd(accum + 1, (double)accc);
  }
}

// ---------------- W f32 -> fragment-linear bf16 ----------------
// WbFrag[((kc*1024 + col)*4 + kg)*8 + i] = W[kc*32 + kg*8 + i][col], 0 for col>=1000
__global__ void k_wconv(const float* __restrict__ W, u16* __restrict__ wb) {
  const int o = blockIdx.x * blockDim.x + threadIdx.x;   // 524288 total
  const int i = o & 7, kg = (o >> 3) & 3, col = (o >> 5) & 1023, kc = o >> 15;
  const int k = kc * 32 + kg * 8 + i;
  float v = (col < NCLS) ? W[(size_t)k * NCLS + col] : 0.f;
  wb[o] = f2bf(v);
}

// ---------------- separation: Gram + exp-sum ----------------
__global__ void k_sep(const float* __restrict__ cen, const float* __restrict__ sq,
                      double* __restrict__ accum) {
  __shared__ float As[16][64];
  __shared__ float Bs[16][64];
  __shared__ float red[4];
  const int bi = blockIdx.x >> 4, bj = blockIdx.x & 15;
  const int tx = threadIdx.x & 15, ty = threadIdx.x >> 4;
  const int lrow = threadIdx.x & 63, lkq = threadIdx.x >> 6;
  float acc[4][4] = {};
  for (int k0 = 0; k0 < HID; k0 += 16) {
    __syncthreads();
    float4 a = *(const float4*)(cen + (size_t)(bi * 64 + lrow) * HID + k0 + lkq * 4);
    float4 b = *(const float4*)(cen + (size_t)(bj * 64 + lrow) * HID + k0 + lkq * 4);
    As[lkq*4+0][lrow] = a.x; As[lkq*4+1][lrow] = a.y; As[lkq*4+2][lrow] = a.z; As[lkq*4+3][lrow] = a.w;
    Bs[lkq*4+0][lrow] = b.x; Bs[lkq*4+1][lrow] = b.y; Bs[lkq*4+2][lrow] = b.z; Bs[lkq*4+3][lrow] = b.w;
    __syncthreads();
    #pragma unroll
    for (int k = 0; k < 16; ++k) {
      float4 av = *(const float4*)&As[k][ty * 4];
      float4 bv = *(const float4*)&Bs[k][tx * 4];
      float ar[4] = {av.x, av.y, av.z, av.w};
      float br[4] = {bv.x, bv.y, bv.z, bv.w};
      #pragma unroll
      for (int r = 0; r < 4; ++r)
        #pragma unroll
        for (int s = 0; s < 4; ++s)
          acc[r][s] = fmaf(ar[r], br[s], acc[r][s]);
    }
  }
  float part = 0.f;
  #pragma unroll
  for (int r = 0; r < 4; ++r) {
    const int i = bi * 64 + ty * 4 + r;
    #pragma unroll
    for (int s = 0; s < 4; ++s) {
      const int j = bj * 64 + tx * 4 + s;
      if (i < NCLS && j < NCLS) {
        float d2 = fmaxf(sq[i] + sq[j] - 2.f * acc[r][s], 0.f);
        float dist = sqrtf(d2);
        part += __expf((i == j ? 1.f : 0.f) - dist);
      }
    }
  }
  #pragma unroll
  for (int s = 32; s; s >>= 1) part += __shfl_xor(part, s);
  if ((threadIdx.x & 63) == 0) red[threadIdx.x >> 6] = part;
  __syncthreads();
  if (threadIdx.x == 0)
    atomicAdd(accum + 2, (double)(red[0] + red[1] + red[2] + red[3]));
}

// ---------------- prep: bf16 panel x = cls + 0.1*noise, pre-swizzled ----------------
// panel[row*512 + koff] holds x[row][koff ^ ((row&7)<<3)] (XOR is an involution on bits 3-5)
__global__ void k_prep(const float* __restrict__ cls, const float* __restrict__ noise,
                       u16* __restrict__ panel) {
  const int nth = gridDim.x * blockDim.x;
  for (int c = blockIdx.x * blockDim.x + threadIdx.x; c < BATCH * 64; c += nth) {
    const int row = c >> 6;
    const int koff = (c & 63) * 8;
    const int k = koff ^ ((row & 7) << 3);
    const float4* cp = (const float4*)(cls   + (size_t)row * HID + k);
    const float4* np = (const float4*)(noise + (size_t)row * HID + k);
    float4 a0 = cp[0], a1 = cp[1];
    float4 n0 = np[0], n1 = np[1];
    uint4 p;
    p.x = (u32)f2bf(fmaf(0.1f, n0.x, a0.x)) | ((u32)f2bf(fmaf(0.1f, n0.y, a0.y)) << 16);
    p.y = (u32)f2bf(fmaf(0.1f, n0.z, a0.z)) | ((u32)f2bf(fmaf(0.1f, n0.w, a0.w)) << 16);
    p.z = (u32)f2bf(fmaf(0.1f, n1.x, a1.x)) | ((u32)f2bf(fmaf(0.1f, n1.y, a1.y)) << 16);
    p.w = (u32)f2bf(fmaf(0.1f, n1.z, a1.z)) | ((u32)f2bf(fmaf(0.1f, n1.w, a1.w)) << 16);
    *(uint4*)&panel[(size_t)row * 512 + koff] = p;
  }
}

// ---------------- GEMM (bf16 MFMA, global_load_lds staging) + fused epilogue ----------------
// BM=32 rows/block (2048 blocks), BN=1024, 8 waves x 128 cols, acc[2][8]=64 f32/lane.
// Phase 1: DMA pre-swizzled A tile into LDS (32 KB of the 64 KB union).
// Phase 2: 16 barrier-free K-steps (B frags stream from L2).
// Phase 3: transpose ln=acc+bias to LDS as bf16 (32x1024, bank-swizzled);
//          single coalesced pass over logits computes diff^2 AND brier (no max-sub).
__global__ __launch_bounds__(512, 4)
void k_gemm(const u16* __restrict__ panel, const float* __restrict__ logits,
            const int* __restrict__ labels, const float* __restrict__ bias,
            const u16* __restrict__ wb, double* __restrict__ accum) {
  __shared__ u16 lds[32 * 1024];   // 64 KB union: phase 1-2 A-panel (first 32 KB), phase 3 ln tile
  const int lane = threadIdx.x & 63;
  const int w = threadIdx.x >> 6;
  const int row0 = blockIdx.x * 32;
  const int l15 = lane & 15, lkg = lane >> 4;

  // ---- phase 1: DMA the pre-swizzled 32x512 bf16 tile into LDS (width-16) ----
  {
    const u16* src = panel + (size_t)blockIdx.x * 16384;
    #pragma unroll
    for (int r = 0; r < 4; ++r) {
      const int seg = r * 8 + w;                    // 1 KB segment per wave-issue
      const u16* g = src + seg * 512 + lane * 8;    // per-lane global source
      u16* l = lds + seg * 512;                     // wave-uniform LDS dest
      __builtin_amdgcn_global_load_lds((const __attribute__((address_space(1))) void*)g,
                                       (__attribute__((address_space(3))) void*)l,
                                       16, 0, 0);
    }
  }
  __syncthreads();

  // ---- phase 2: 16 barrier-free K-steps ----
  f32x4 acc[2][8] = {};
  const int swr = (l15 & 7) << 3;
  for (int kc = 0; kc < 16; ++kc) {
    bf16x8 af0 = *(const bf16x8*)&lds[(l15)      * 512 + ((kc * 32 + lkg * 8) ^ swr)];
    bf16x8 af1 = *(const bf16x8*)&lds[(16 + l15) * 512 + ((kc * 32 + lkg * 8) ^ swr)];
    const u16* bbase = wb + (size_t)kc * 32768 + (w * 128 + l15) * 32 + lkg * 8;
    #pragma unroll
    for (int ct = 0; ct < 8; ++ct) {
      bf16x8 bfrag = *(const bf16x8*)(bbase + ct * 512);
      acc[0][ct] = __builtin_amdgcn_mfma_f32_16x16x32_bf16(af0, bfrag, acc[0][ct], 0, 0, 0);
      acc[1][ct] = __builtin_amdgcn_mfma_f32_16x16x32_bf16(af1, bfrag, acc[1][ct], 0, 0, 0);
    }
  }

  // ---- phase 3a: transpose ln = acc + bias into LDS as bf16 ----
  // C layout: col = w*128 + ct*16 + l15, rowloc = rt*16 + lkg*4 + r.
  // byte addr = rowloc*2048 + ((col*2) ^ (((rowloc>>2)&3)<<5)): the 4 lkg groups
  // land on disjoint bank quarters -> conflict-free wave64 writes.
  __syncthreads();              // all phase-2 reads of lds complete
  char* ldsb = (char*)lds;
  #pragma unroll
  for (int ct = 0; ct < 8; ++ct) {
    const int col = w * 128 + ct * 16 + l15;
    if (col < NCLS) {
      const float bc = bias[col];
      #pragma unroll
      for (int rt = 0; rt < 2; ++rt) {
        #pragma unroll
        for (int r = 0; r < 4; ++r) {
          const int rowloc = rt * 16 + lkg * 4 + r;
          const int byte = rowloc * 2048 + ((col * 2) ^ ((rowloc & 12) << 3));
          *(u16*)(ldsb + byte) = f2bf(acc[rt][ct][r] + bc);
        }
      }
    }
  }
  __syncthreads();

  // ---- phase 3b: single coalesced pass over logits: diff^2 + brier (no max-sub) ----
  float spart = 0.f, bpart = 0.f;
  for (int j = 0; j < 4; ++j) {
    const int rowloc = w * 4 + j;
    const int row = row0 + rowloc;
    const int swz = (rowloc & 12) << 3;
    const char* lnrow = ldsb + rowloc * 2048;
    const float4* lr = (const float4*)(logits + (size_t)row * NCLS);
    const int lab2 = labels[row];
    float S = 0.f, S2 = 0.f, el = 0.f;
    #pragma unroll
    for (int it = 0; it < 4; ++it) {
      const int f = it * 64 + lane;
      if (f < 250) {
        float4 lg = lr[f];
        const u32* lp = (const u32*)(lnrow + ((f * 8) ^ swz));
        u32 w0 = lp[0], w1 = lp[1];
        float n0 = __uint_as_float(w0 << 16);
        float n1 = __uint_as_float(w0 & 0xffff0000u);
        float n2 = __uint_as_float(w1 << 16);
        float n3 = __uint_as_float(w1 & 0xffff0000u);
        float d0 = n0 - lg.x, d1 = n1 - lg.y, d2 = n2 - lg.z, d3 = n3 - lg.w;
        spart += d0 * d0 + d1 * d1 + d2 * d2 + d3 * d3;
        float e0 = __expf(lg.x), e1 = __expf(lg.y), e2 = __expf(lg.z), e3 = __expf(lg.w);
        S += e0 + e1 + e2 + e3;
        S2 += e0 * e0 + e1 * e1 + e2 * e2 + e3 * e3;
        const int c0 = f * 4;
        if (c0     == lab2) el = e0;
        if (c0 + 1 == lab2) el = e1;
        if (c0 + 2 == lab2) el = e2;
        if (c0 + 3 == lab2) el = e3;
      }
    }
    #pragma unroll
    for (int s = 32; s; s >>= 1) { S += __shfl_xor(S, s); S2 += __shfl_xor(S2, s); el += __shfl_xor(el, s); }
    bpart += S2 / (S * S) - 2.f * el / S + 1.f;
  }
  #pragma unroll
  for (int s = 32; s; s >>= 1) { spart += __shfl_xor(spart, s); bpart += __shfl_xor(bpart, s); }

  // ---- block reduce (reuse lds) + atomics ----
  __syncthreads();                    // all ln reads done before reuse
  float* redf = (float*)lds;
  if (lane == 0) { redf[w] = spart; redf[8 + w] = bpart; }
  __syncthreads();
  if (threadIdx.x == 0) {
    float st = 0.f, br = 0.f;
    #pragma unroll
    for (int i = 0; i < 8; ++i) { st += redf[i]; br += redf[8 + i]; }
    atomicAdd(accum + 0, (double)st);
    atomicAdd(accum + 3, (double)br);
  }
}

// ---------------- fallback fused stab (round-4 path, used if ws too small) ----------------
__global__ __launch_bounds__(512, 4)
void k_stab_fb(const float* __restrict__ cls, const float* __restrict__ noise,
               const float* __restrict__ logits, const int* __restrict__ labels,
               const float* __restrict__ bias, const u16* __restrict__ wb,
               double* __restrict__ accum) {
  __shared__ u16 As[32 * 512];
  const int lane = threadIdx.x & 63;
  const int w = threadIdx.x >> 6;
  const int row0 = blockIdx.x * 32;
  const int l15 = lane & 15, lkg = lane >> 4;
  {
    const int row_loc = threadIdx.x >> 4;
    const int k0 = (threadIdx.x & 15) * 32;
    const float4* cp = (const float4*)(cls   + (size_t)(row0 + row_loc) * HID + k0);
    const float4* np = (const float4*)(noise + (size_t)(row0 + row_loc) * HID + k0);
    const int sw = (row_loc & 7) << 3;
    #pragma unroll
    for (int q = 0; q < 4; ++q) {
      float4 a0 = cp[q * 2], a1 = cp[q * 2 + 1];
      float4 n0 = np[q * 2], n1 = np[q * 2 + 1];
      uint4 p;
      p.x = (u32)f2bf(fmaf(0.1f, n0.x, a0.x)) | ((u32)f2bf(fmaf(0.1f, n0.y, a0.y)) << 16);
      p.y = (u32)f2bf(fmaf(0.1f, n0.z, a0.z)) | ((u32)f2bf(fmaf(0.1f, n0.w, a0.w)) << 16);
      p.z = (u32)f2bf(fmaf(0.1f, n1.x, a1.x)) | ((u32)f2bf(fmaf(0.1f, n1.y, a1.y)) << 16);
      p.w = (u32)f2bf(fmaf(0.1f, n1.z, a1.z)) | ((u32)f2bf(fmaf(0.1f, n1.w, a1.w)) << 16);
      *(uint4*)&As[row_loc * 512 + ((k0 + q * 8) ^ sw)] = p;
    }
  }
  __syncthreads();
  f32x4 acc[2][8] = {};
  const int swr = (l15 & 7) << 3;
  for (int kc = 0; kc < 16; ++kc) {
    bf16x8 af0 = *(const bf16x8*)&As[(l15)      * 512 + ((kc * 32 + lkg * 8) ^ swr)];
    bf16x8 af1 = *(const bf16x8*)&As[(16 + l15) * 512 + ((kc * 32 + lkg * 8) ^ swr)];
    const u16* bbase = wb + (size_t)kc * 32768 + (w * 128 + l15) * 32 + lkg * 8;
    #pragma unroll
    for (int ct = 0; ct < 8; ++ct) {
      bf16x8 bfrag = *(const bf16x8*)(bbase + ct * 512);
      acc[0][ct] = __builtin_amdgcn_mfma_f32_16x16x32_bf16(af0, bfrag, acc[0][ct], 0, 0, 0);
      acc[1][ct] = __builtin_amdgcn_mfma_f32_16x16x32_bf16(af1, bfrag, acc[1][ct], 0, 0, 0);
    }
  }
  float bpart = 0.f;
  for (int j = 0; j < 4; ++j) {
    const int row = row0 + w * 4 + j;
    const float4* lr = (const float4*)(logits + (size_t)row * NCLS);
    float4 v[4];
    float m = -3.4e38f;
    #pragma unroll
    for (int it = 0; it < 4; ++it) {
      const int f = it * 64 + lane;
      if (f < 250) {
        v[it] = lr[f];
        m = fmaxf(m, fmaxf(fmaxf(v[it].x, v[it].y), fmaxf(v[it].z, v[it].w)));
      }
    }
    #pragma unroll
    for (int s = 32; s; s >>= 1) m = fmaxf(m, __shfl_xor(m, s));
    const int lab2 = labels[row];
    float S = 0.f, S2 = 0.f, el = 0.f;
    #pragma unroll
    for (int it = 0; it < 4; ++it) {
      const int f = it * 64 + lane;
      if (f < 250) {
        float e0 = __expf(v[it].x - m);
        float e1 = __expf(v[it].y - m);
        float e2 = __expf(v[it].z - m);
        float e3 = __expf(v[it].w - m);
        S += e0 + e1 + e2 + e3;
        S2 += e0 * e0 + e1 * e1 + e2 * e2 + e3 * e3;
        const int c0 = f * 4;
        if (c0     == lab2) el = e0;
        if (c0 + 1 == lab2) el = e1;
        if (c0 + 2 == lab2) el = e2;
        if (c0 + 3 == lab2) el = e3;
      }
    }
    #pragma unroll
    for (int s = 32; s; s >>= 1) { S += __shfl_xor(S, s); S2 += __shfl_xor(S2, s); el += __shfl_xor(el, s); }
    bpart += S2 / (S * S) - 2.f * el / S + 1.f;
  }
  float spart = 0.f;
  #pragma unroll
  for (int ct = 0; ct < 8; ++ct) {
    const int col = w * 128 + ct * 16 + l15;
    if (col < NCLS) {
      const float bc = bias[col];
      #pragma unroll
      for (int rt = 0; rt < 2; ++rt) {
        const int rbase = row0 + rt * 16 + lkg * 4;
        #pragma unroll
        for (int r = 0; r < 4; ++r) {
          float d = acc[rt][ct][r] + bc - logits[(size_t)(rbase + r) * NCLS + col];
          spart += d * d;
        }
      }
    }
  }
  #pragma unroll
  for (int s = 32; s; s >>= 1) { spart += __shfl_xor(spart, s); bpart += __shfl_xor(bpart, s); }
  __syncthreads();
  float* redf = (float*)As;
  if (lane == 0) { redf[w] = spart; redf[8 + w] = bpart; }
  __syncthreads();
  if (threadIdx.x == 0) {
    float st = 0.f, br = 0.f;
    #pragma unroll
    for (int i = 0; i < 8; ++i) { st += redf[i]; br += redf[8 + i]; }
    atomicAdd(accum + 0, (double)st);
    atomicAdd(accum + 3, (double)br);
  }
}

// ---------------- combine ----------------
__global__ void k_final(const double* __restrict__ accum, float* __restrict__ out) {
  if (threadIdx.x == 0) {
    double stab   = accum[0] / ((double)BATCH * (double)NCLS);
    double center = accum[1] / ((double)BATCH * (double)HID);
    double sep    = accum[2] - (double)NCLS;
    double brier  = accum[3] / (double)BATCH;
    double total  = 1.0 * stab + 0.1 * center + 0.01 * sep + 1.0 * brier;
    out[0] = (float)total;
    out[1] = (float)stab;
    out[2] = (float)center;
    out[3] = (float)sep;
    out[4] = (float)brier;
  }
}

extern "C" void kernel_launch(void* const* d_in, const int* in_sizes, int n_in,
                              void* d_out, int out_size, void* d_ws, size_t ws_size,
                              hipStream_t stream) {
  const float* cls    = (const float*)d_in[0];
  const float* logits = (const float*)d_in[1];
  const int*   labels = (const int*)d_in[2];
  const float* W      = (const float*)d_in[3];
  const float* bias   = (const float*)d_in[4];
  const float* noise  = (const float*)d_in[5];
  const float* cen_in = (const float*)d_in[6];
  float* out = (float*)d_out;
  char* ws = (char*)d_ws;
  if (ws_size < (size_t)WS_END) return;  // fail visibly (out stays poisoned)

  int*    counts  = (int*)(ws + 0);
  double* accum   = (double*)(ws + 4096);
  float*  sq      = (float*)(ws + 8192);
  int*    offsets = (int*)(ws + 12288);
  int*    order   = (int*)(ws + 16384);
  float*  cen     = (float*)(ws + 278528);
  u16*    wb      = (u16*)(ws + 2375680);
  u16*    panel   = (u16*)(ws + 3424256);

  hipMemsetAsync(ws, 0, 4160, stream);   // zero counts + accum
  hipLaunchKernelGGL(k_hist,    dim3(256),  dim3(256), 0, stream, labels, counts);
  hipLaunchKernelGGL(k_wconv,   dim3(2048), dim3(256), 0, stream, W, wb);
  hipLaunchKernelGGL(k_scan,    dim3(1),    dim3(1024),0, stream, counts, offsets);
  hipLaunchKernelGGL(k_scatter, dim3(256),  dim3(256), 0, stream, labels, offsets, order);
  hipLaunchKernelGGL(k_segsum,  dim3(1024), dim3(512), 0, stream, cls, order, offsets, counts, cen_in, cen, sq, accum);
  hipLaunchKernelGGL(k_sep,     dim3(256),  dim3(256), 0, stream, cen, sq, accum);
  if (ws_size >= (size_t)WS_BIG) {
    hipLaunchKernelGGL(k_prep,  dim3(2048), dim3(256), 0, stream, cls, noise, panel);
    hipLaunchKernelGGL(k_gemm,  dim3(2048), dim3(512), 0, stream, panel, logits, labels, bias, wb, accum);
  } else {
    hipLaunchKernelGGL(k_stab_fb, dim3(2048), dim3(512), 0, stream, cls, noise, logits, labels, bias, wb, accum);
  }
  hipLaunchKernelGGL(k_final,   dim3(1),    dim3(64),  0, stream, accum, out);
}